// Round 9
// baseline (559.287 us; speedup 1.0000x reference)
//
#include <hip/hip_runtime.h>

#define HH 512
#define WW 512
#define NPIX (HH * WW)          // 262144
#define NIMG 16
#define KPTS 1024
#define NWORDS (NPIX / 64)      // 4096 u64 mask words per image

// ---------------------------------------------------------------------------
// Kernel 1: binarize + uniform LBP (P=8,R=1) + ballot-pack mask bits
// ---------------------------------------------------------------------------
__global__ void lbp_kernel(const float* __restrict__ mo,
                           const float* __restrict__ lb,
                           unsigned long long* __restrict__ maskbits) {
#pragma clang fp contract(off)
    int m = blockIdx.y;                    // image 0..15: even=pred, odd=mask
    int pix = blockIdx.x * blockDim.x + threadIdx.x;   // 0..262143
    int r = pix >> 9, c = pix & 511;
    int sample = m >> 1;
    const float* img = (m & 1) ? (lb + sample * NPIX) : (mo + sample * NPIX);
    float thr = (m & 1) ? 0.5f : 0.0f;     // sigmoid(x)>0.5 <=> x>0

    float center = img[pix] > thr ? 1.0f : 0.0f;

    const float A = 0.70710678f;           // np.round(sin/cos, 8)
    const float drs[8] = {0.f, -A, -1.f, -A, 0.f,  A, 1.f, A};
    const float dcs[8] = {1.f,  A,  0.f, -A, -1.f, -A, 0.f, A};

    unsigned bb = 0u;
#pragma unroll
    for (int k = 0; k < 8; k++) {
        float rr = (float)r + drs[k];
        float cc = (float)c + dcs[k];
        float r0 = floorf(rr), c0 = floorf(cc);
        float fr = rr - r0,   fc = cc - c0;
        int r0i = (int)r0; r0i = max(0, min(HH - 1, r0i));
        int c0i = (int)c0; c0i = max(0, min(WW - 1, c0i));
        int r1i = min(HH - 1, r0i + 1);
        int c1i = min(WW - 1, c0i + 1);
        float g00 = img[r0i * WW + c0i] > thr ? 1.0f : 0.0f;
        float g01 = img[r0i * WW + c1i] > thr ? 1.0f : 0.0f;
        float g10 = img[r1i * WW + c0i] > thr ? 1.0f : 0.0f;
        float g11 = img[r1i * WW + c1i] > thr ? 1.0f : 0.0f;
        float s1 = (1.0f - fc) * g00 + fc * g01;
        float s2 = (1.0f - fc) * g10 + fc * g11;
        float smp = (1.0f - fr) * s1 + fr * s2;
        if (smp - center >= 0.0f) bb |= (1u << k);
    }
    unsigned rol = ((bb << 1) | (bb >> 7)) & 0xFFu;
    int changes = __popc(bb ^ rol);
    int s = __popc(bb);
    bool maskbit = (changes <= 2) && (s < 5);   // lbp < THR(=5)

    unsigned long long w = __ballot(maskbit);
    if ((threadIdx.x & 63) == 0)
        maskbits[m * NWORDS + (pix >> 6)] = w;
}

// ---------------------------------------------------------------------------
// Kernel 2: stable row-major compaction to K=1024 packed points per image
// pts entry: (r<<16)|c ; zero-padded. Shfl scan + uniform early-exit once
// K points are found (random inputs -> chunk 0 already has ~2x K).
// ---------------------------------------------------------------------------
__global__ void select_kernel(const unsigned long long* __restrict__ maskbits,
                              unsigned* __restrict__ ptsG) {
    __shared__ unsigned swv[4];
    int m = blockIdx.x, tid = threadIdx.x;
    int lane = tid & 63, wid = tid >> 6;

    for (int i = tid; i < KPTS; i += 256) ptsG[m * KPTS + i] = 0u;
    __syncthreads();

    unsigned running = 0;
    for (int ch = 0; ch < 16; ch++) {
        int w = ch * 256 + tid;
        unsigned long long word = maskbits[m * NWORDS + w];
        unsigned cnt = (unsigned)__popcll(word);

        unsigned x = cnt;                    // intra-wave inclusive scan
#pragma unroll
        for (int d = 1; d < 64; d <<= 1) {
            unsigned y = (unsigned)__shfl_up((int)x, d, 64);
            x += (lane >= d) ? y : 0u;
        }
        if (lane == 63) swv[wid] = x;
        __syncthreads();
        unsigned woff = 0, total = 0;
#pragma unroll
        for (int ww = 0; ww < 4; ww++) {
            unsigned t = swv[ww];
            total += t;
            woff += (ww < wid) ? t : 0u;
        }
        unsigned rank = running + woff + x - cnt;   // exclusive prefix
        while (word) {
            int b = __builtin_ctzll(word);
            word &= word - 1;
            if (rank < (unsigned)KPTS) {
                unsigned p = (unsigned)(w * 64 + b);
                unsigned rr = p >> 9, cc = p & 511u;
                ptsG[m * KPTS + rank] = (rr << 16) | cc;
            }
            rank++;
        }
        running += total;
        if (running >= (unsigned)KPTS) break;   // uniform -> safe
        __syncthreads();   // protect swv before next chunk
    }
}

// ---------------------------------------------------------------------------
// Kernel 3 (phase 1): single-wave Prim per image, RECORD-ONLY, ZERO LDS.
// Model (R6/R8 fit): T_iter = 284ns fixed + 0.94ns/VALU -> cut both:
//  - uniform SWITCH over wslot: 1 readlane + 1 kill-cndmask (was SEL16's
//    15 cndmask + 16 per-slot kills)
//  - edge stores batched: accumulate in a register lane, one full-wave
//    coalesced store per 64 iters (no per-iter exec dance / store guards)
// key = (d2<<10)|idx via shifted coords + sdot2-accumulate (exact).
// ---------------------------------------------------------------------------
typedef short v2s __attribute__((ext_vector_type(2)));

__device__ __forceinline__ int dist2_packed(unsigned a, unsigned b) {
#if __has_builtin(__builtin_amdgcn_sdot2)
    v2s d = __builtin_bit_cast(v2s, a) - __builtin_bit_cast(v2s, b);
    return __builtin_amdgcn_sdot2(d, d, 0, false);
#else
    int dr = (int)(a >> 16) - (int)(b >> 16);
    int dc = (int)(a & 0xFFFFu) - (int)(b & 0xFFFFu);
    return __mul24(dr, dr) + __mul24(dc, dc);
#endif
}

template <int CTRL>
__device__ __forceinline__ unsigned umin_dpp(unsigned x) {
    unsigned o = (unsigned)__builtin_amdgcn_update_dpp((int)x, (int)x, CTRL,
                                                       0xf, 0xf, false);
    return o < x ? o : x;
}

__device__ __forceinline__ unsigned umin3(unsigned a, unsigned b, unsigned c) {
    unsigned t = a < b ? a : b;          // fuses to v_min3_u32
    return t < c ? t : c;
}

// key from SHIFTED coords: sdot2 accumulates idx -> (d2<<10)+idx == (d2<<10)|idx
__device__ __forceinline__ unsigned mk_key(unsigned ps, unsigned qs, unsigned idx) {
#if __has_builtin(__builtin_amdgcn_sdot2)
    v2s d = __builtin_bit_cast(v2s, ps) - __builtin_bit_cast(v2s, qs);
    return (unsigned)__builtin_amdgcn_sdot2(d, d, (int)idx, false);
#else
    int dr = (int)(short)(ps >> 16) - (int)(short)(qs >> 16);
    int dc = (int)(short)(ps & 0xFFFFu) - (int)(short)(qs & 0xFFFFu);
    return (unsigned)(dr * dr + dc * dc + (int)idx);
#endif
}

#define SLOT_INIT(s, ps, ks, is)                                          \
    is = (unsigned)((s << 6) | lane);                                     \
    ps = base[(s << 6) | lane] << 5;    /* halves: r<<5 | c<<5 */         \
    ks = mk_key(ps, pt0s, is);

#define SLOT_UPD(s, ps, ks, is)                                           \
    { unsigned _nk = mk_key(ps, pjs, is);                                 \
      ks = (unsigned)min((int)ks, (int)_nk); }  /* v_min_i32: -1 wins */

#define INLANE_MIN16(res)                                                 \
    { unsigned _m0 = umin3(k0, k1, k2);                                   \
      unsigned _m1 = umin3(k3, k4, k5);                                   \
      unsigned _m2 = umin3(k6, k7, k8);                                   \
      unsigned _m3 = umin3(k9, k10, k11);                                 \
      unsigned _m4 = umin3(k12, k13, k14);                                \
      unsigned _ra = umin3(_m0, _m1, _m2);                                \
      unsigned _rb = umin3(_m3, _m4, k15);                                \
      res = _ra < _rb ? _ra : _rb; }

#define PIN16(P) asm volatile("" :                                        \
    "+v"(P##0), "+v"(P##1), "+v"(P##2),  "+v"(P##3),                      \
    "+v"(P##4), "+v"(P##5), "+v"(P##6),  "+v"(P##7),                      \
    "+v"(P##8), "+v"(P##9), "+v"(P##10), "+v"(P##11),                     \
    "+v"(P##12), "+v"(P##13), "+v"(P##14), "+v"(P##15))

#define ARM(s, ps, ks)                                                    \
    case s: pjs = (unsigned)__builtin_amdgcn_readlane((int)ps, wlane);    \
            ks = hit ? 0xFFFFFFFFu : ks;                                  \
            break;

__global__ __launch_bounds__(64, 1) void mst_kernel(const unsigned* __restrict__ ptsG,
                                                    unsigned* __restrict__ edgesG) {
    int lane = threadIdx.x;          // 0..63
    int m = blockIdx.x;
    const unsigned* base = ptsG + m * KPTS;
    unsigned pt0s = base[0] << 5;    // self point 0, shifted (uniform)

    unsigned k0,k1,k2,k3,k4,k5,k6,k7,k8,k9,k10,k11,k12,k13,k14,k15;
    unsigned p0,p1,p2,p3,p4,p5,p6,p7,p8,p9,p10,p11,p12,p13,p14,p15;
    unsigned i0,i1,i2,i3,i4,i5,i6,i7,i8,i9,i10,i11,i12,i13,i14,i15;

    SLOT_INIT(0,  p0,  k0,  i0);   SLOT_INIT(1,  p1,  k1,  i1);
    SLOT_INIT(2,  p2,  k2,  i2);   SLOT_INIT(3,  p3,  k3,  i3);
    SLOT_INIT(4,  p4,  k4,  i4);   SLOT_INIT(5,  p5,  k5,  i5);
    SLOT_INIT(6,  p6,  k6,  i6);   SLOT_INIT(7,  p7,  k7,  i7);
    SLOT_INIT(8,  p8,  k8,  i8);   SLOT_INIT(9,  p9,  k9,  i9);
    SLOT_INIT(10, p10, k10, i10);  SLOT_INIT(11, p11, k11, i11);
    SLOT_INIT(12, p12, k12, i12);  SLOT_INIT(13, p13, k13, i13);
    SLOT_INIT(14, p14, k14, i14);  SLOT_INIT(15, p15, k15, i15);

    k0 = (lane == 0) ? 0xFFFFFFFFu : k0;   // in_tree[0] = True

    unsigned* eout = edgesG + m * KPTS;
    unsigned rk;
    INLANE_MIN16(rk);

    unsigned acc = 0;                // per-lane edge accumulator (batch of 64)

    for (int it = 0; it < KPTS - 1; it++) {
        PIN16(p); PIN16(k); PIN16(i);

        // ---- wave-64 min: 4 DPP row-folds + 4 readlane + scalar min ----
        rk = umin_dpp<0x111>(rk);   // row_shr:1
        rk = umin_dpp<0x112>(rk);   // row_shr:2
        rk = umin_dpp<0x114>(rk);   // row_shr:4
        rk = umin_dpp<0x118>(rk);   // row_shr:8 -> lane15 of each 16-row
        unsigned q0 = (unsigned)__builtin_amdgcn_readlane((int)rk, 15);
        unsigned q1 = (unsigned)__builtin_amdgcn_readlane((int)rk, 31);
        unsigned q2 = (unsigned)__builtin_amdgcn_readlane((int)rk, 47);
        unsigned q3 = (unsigned)__builtin_amdgcn_readlane((int)rk, 63);
        unsigned wa = q0 < q1 ? q0 : q1;
        unsigned wb = q2 < q3 ? q2 : q3;
        unsigned wk = wa < wb ? wa : wb;     // scalar, uniform

        unsigned j = wk & 1023u;
        int wslot = (int)(j >> 6);
        int wlane = (int)(j & 63u);
        bool hit = (lane == wlane);

        // ---- uniform switch: 1 readlane + 1 kill (was SEL16 + 16 kills) ----
        unsigned pjs;
        switch (wslot) {
            ARM(0,  p0,  k0)   ARM(1,  p1,  k1)   ARM(2,  p2,  k2)
            ARM(3,  p3,  k3)   ARM(4,  p4,  k4)   ARM(5,  p5,  k5)
            ARM(6,  p6,  k6)   ARM(7,  p7,  k7)   ARM(8,  p8,  k8)
            ARM(9,  p9,  k9)   ARM(10, p10, k10)  ARM(11, p11, k11)
            ARM(12, p12, k12)  ARM(13, p13, k13)
            ARM(14, p14, k14)
            default: pjs = (unsigned)__builtin_amdgcn_readlane((int)p15, wlane);
                     k15 = hit ? 0xFFFFFFFFu : k15;
                     break;
        }

        // ---- edge record: accumulate, bulk-store every 64 iters ----
        acc = (lane == (it & 63)) ? wk : acc;
        if ((it & 63) == 63)                 // uniform; full-wave coalesced
            eout[(it - 63) + lane] = acc;

        // ---- decrease-key (3 VALU per slot, kill already done) ----
        SLOT_UPD(0,  p0,  k0,  i0);   SLOT_UPD(1,  p1,  k1,  i1);
        SLOT_UPD(2,  p2,  k2,  i2);   SLOT_UPD(3,  p3,  k3,  i3);
        SLOT_UPD(4,  p4,  k4,  i4);   SLOT_UPD(5,  p5,  k5,  i5);
        SLOT_UPD(6,  p6,  k6,  i6);   SLOT_UPD(7,  p7,  k7,  i7);
        SLOT_UPD(8,  p8,  k8,  i8);   SLOT_UPD(9,  p9,  k9,  i9);
        SLOT_UPD(10, p10, k10, i10);  SLOT_UPD(11, p11, k11, i11);
        SLOT_UPD(12, p12, k12, i12);  SLOT_UPD(13, p13, k13, i13);
        SLOT_UPD(14, p14, k14, i14);  SLOT_UPD(15, p15, k15, i15);

        INLANE_MIN16(rk);                    // next iteration's per-lane min
    }
    // tail: iterations 960..1022 filled lanes 0..62 of the last batch
    if (lane < 63) eout[960 + lane] = acc;
}

// ---------------------------------------------------------------------------
// Kernel 4 (phase 2): recover src per edge + per-edge (Dp-Dm)^2.
// src[j] = earliest-extracted v with d2(v,j)==d2p (exact-int match) —
// provably identical to the reference's strict-'<' update history.
// ---------------------------------------------------------------------------
__global__ void recover_kernel(const unsigned* __restrict__ ptsG,
                               const unsigned* __restrict__ edgesG,
                               float* __restrict__ contrib) {
    __shared__ unsigned sS[KPTS];
    __shared__ unsigned sO[KPTS];
    __shared__ unsigned short sT[KPTS];   // extraction time + 1 (0 = root)
    int g = blockIdx.x, m = blockIdx.y;
    int tid = threadIdx.x;
    int partner = m ^ 1;

    for (int i = tid; i < KPTS; i += 256) {
        sS[i] = ptsG[m * KPTS + i];
        sO[i] = ptsG[partner * KPTS + i];
    }
    for (int e = tid; e < KPTS - 1; e += 256) {
        unsigned wkk = edgesG[m * KPTS + e];
        sT[wkk & 1023u] = (unsigned short)(e + 1);
    }
    if (tid == 0) sT[0] = 0;
    __syncthreads();

    int lane = tid & 63, w = tid >> 6;
    for (int k = 0; k < 16; k++) {
        int e = g * 64 + w * 16 + k;
        if (e >= KPTS - 1) break;            // only e=1023 (g=15,w=3,k=15)
        unsigned wk = edgesG[m * KPTS + e];
        unsigned j = wk & 1023u;
        unsigned d2p = wk >> 10;
        unsigned pj = sS[j];
        unsigned te1 = (unsigned)(e + 1);

        unsigned best = 0xFFFFFFFFu;
#pragma unroll
        for (int i = 0; i < 16; i++) {
            int v = i * 64 + lane;
            unsigned pv = sS[v];
            int d2 = dist2_packed(pv, pj);
            unsigned tv1 = (unsigned)sT[v];
            bool qual = ((unsigned)d2 == d2p) && (tv1 < te1);
            unsigned cand = qual ? ((tv1 << 10) | (unsigned)v) : 0xFFFFFFFFu;
            best = cand < best ? cand : best;
        }
#pragma unroll
        for (int dd = 32; dd; dd >>= 1) {
            unsigned o = (unsigned)__shfl_xor((int)best, dd, 64);
            best = o < best ? o : best;
        }
        unsigned vsrc = best & 1023u;
        if (lane == 0) {
            unsigned oj = sO[j], os = sO[vsrc];
            float Dp = __fsqrt_rn((float)d2p);
            float Dm = __fsqrt_rn((float)dist2_packed(oj, os));
            float diff = Dp - Dm;
            contrib[m * (KPTS - 1) + e] = diff * diff;
        }
    }
}

// ---------------------------------------------------------------------------
// Kernel 5: per-image f64 sum (extraction order, deterministic) -> loss
// ---------------------------------------------------------------------------
__global__ void final_kernel(const float* __restrict__ contrib,
                             float* __restrict__ out) {
    __shared__ double part[NIMG];
    int t = threadIdx.x;
    if (t < NIMG) {
        double s = 0.0;
        for (int e = 0; e < KPTS - 1; e++)
            s += (double)contrib[t * (KPTS - 1) + e];
        part[t] = sqrt(s);
    }
    __syncthreads();
    if (t == 0) {
        double tot = 0.0;
        for (int i = 0; i < NIMG; i++) tot += part[i];
        out[0] = (float)(0.1 * tot / 8.0);
    }
}

// ---------------------------------------------------------------------------
// ws layout:
//   [0,512K)     maskbits (lbp->select), then DEAD:
//   [0,64K)      edgesG   (mst->recover)   — overlaps dead maskbits
//   [64K,128K)   contrib  (recover->final) — overlaps dead maskbits
//   [512K,576K)  ptsG     (select->mst/recover)
// ---------------------------------------------------------------------------
extern "C" void kernel_launch(void* const* d_in, const int* in_sizes, int n_in,
                              void* d_out, int out_size, void* d_ws, size_t ws_size,
                              hipStream_t stream) {
    const float* mo = (const float*)d_in[1];   // model_output
    const float* lb = (const float*)d_in[2];   // labels

    unsigned long long* maskbits = (unsigned long long*)d_ws;
    unsigned* edgesG = (unsigned*)d_ws;
    float* contrib = (float*)((char*)d_ws + (size_t)64 * 1024);
    unsigned* ptsG = (unsigned*)((char*)d_ws + (size_t)NIMG * NWORDS * 8);
    float* out = (float*)d_out;

    lbp_kernel<<<dim3(NPIX / 256, NIMG), 256, 0, stream>>>(mo, lb, maskbits);
    select_kernel<<<NIMG, 256, 0, stream>>>(maskbits, ptsG);
    mst_kernel<<<NIMG, 64, 0, stream>>>(ptsG, edgesG);
    recover_kernel<<<dim3(16, NIMG), 256, 0, stream>>>(ptsG, edgesG, contrib);
    final_kernel<<<1, 64, 0, stream>>>(contrib, out);
}

// Round 10
// 450.128 us; speedup vs baseline: 1.2425x; 1.2425x over previous
//
#include <hip/hip_runtime.h>

#define HH 512
#define WW 512
#define NPIX (HH * WW)          // 262144
#define NIMG 16
#define KPTS 1024
#define NWORDS (NPIX / 64)      // 4096 u64 mask words per image

// ---------------------------------------------------------------------------
// Kernel 1: binarize + uniform LBP (P=8,R=1) + ballot-pack mask bits
// ---------------------------------------------------------------------------
__global__ void lbp_kernel(const float* __restrict__ mo,
                           const float* __restrict__ lb,
                           unsigned long long* __restrict__ maskbits) {
#pragma clang fp contract(off)
    int m = blockIdx.y;                    // image 0..15: even=pred, odd=mask
    int pix = blockIdx.x * blockDim.x + threadIdx.x;   // 0..262143
    int r = pix >> 9, c = pix & 511;
    int sample = m >> 1;
    const float* img = (m & 1) ? (lb + sample * NPIX) : (mo + sample * NPIX);
    float thr = (m & 1) ? 0.5f : 0.0f;     // sigmoid(x)>0.5 <=> x>0

    float center = img[pix] > thr ? 1.0f : 0.0f;

    const float A = 0.70710678f;           // np.round(sin/cos, 8)
    const float drs[8] = {0.f, -A, -1.f, -A, 0.f,  A, 1.f, A};
    const float dcs[8] = {1.f,  A,  0.f, -A, -1.f, -A, 0.f, A};

    unsigned bb = 0u;
#pragma unroll
    for (int k = 0; k < 8; k++) {
        float rr = (float)r + drs[k];
        float cc = (float)c + dcs[k];
        float r0 = floorf(rr), c0 = floorf(cc);
        float fr = rr - r0,   fc = cc - c0;
        int r0i = (int)r0; r0i = max(0, min(HH - 1, r0i));
        int c0i = (int)c0; c0i = max(0, min(WW - 1, c0i));
        int r1i = min(HH - 1, r0i + 1);
        int c1i = min(WW - 1, c0i + 1);
        float g00 = img[r0i * WW + c0i] > thr ? 1.0f : 0.0f;
        float g01 = img[r0i * WW + c1i] > thr ? 1.0f : 0.0f;
        float g10 = img[r1i * WW + c0i] > thr ? 1.0f : 0.0f;
        float g11 = img[r1i * WW + c1i] > thr ? 1.0f : 0.0f;
        float s1 = (1.0f - fc) * g00 + fc * g01;
        float s2 = (1.0f - fc) * g10 + fc * g11;
        float smp = (1.0f - fr) * s1 + fr * s2;
        if (smp - center >= 0.0f) bb |= (1u << k);
    }
    unsigned rol = ((bb << 1) | (bb >> 7)) & 0xFFu;
    int changes = __popc(bb ^ rol);
    int s = __popc(bb);
    bool maskbit = (changes <= 2) && (s < 5);   // lbp < THR(=5)

    unsigned long long w = __ballot(maskbit);
    if ((threadIdx.x & 63) == 0)
        maskbits[m * NWORDS + (pix >> 6)] = w;
}

// ---------------------------------------------------------------------------
// Kernel 2: stable row-major compaction to K=1024 packed points per image
// pts entry: (r<<16)|c ; zero-padded. Shfl scan + uniform early-exit once
// K points are found (random inputs -> chunk 0 already has ~2x K).
// ---------------------------------------------------------------------------
__global__ void select_kernel(const unsigned long long* __restrict__ maskbits,
                              unsigned* __restrict__ ptsG) {
    __shared__ unsigned swv[4];
    int m = blockIdx.x, tid = threadIdx.x;
    int lane = tid & 63, wid = tid >> 6;

    for (int i = tid; i < KPTS; i += 256) ptsG[m * KPTS + i] = 0u;
    __syncthreads();

    unsigned running = 0;
    for (int ch = 0; ch < 16; ch++) {
        int w = ch * 256 + tid;
        unsigned long long word = maskbits[m * NWORDS + w];
        unsigned cnt = (unsigned)__popcll(word);

        unsigned x = cnt;                    // intra-wave inclusive scan
#pragma unroll
        for (int d = 1; d < 64; d <<= 1) {
            unsigned y = (unsigned)__shfl_up((int)x, d, 64);
            x += (lane >= d) ? y : 0u;
        }
        if (lane == 63) swv[wid] = x;
        __syncthreads();
        unsigned woff = 0, total = 0;
#pragma unroll
        for (int ww = 0; ww < 4; ww++) {
            unsigned t = swv[ww];
            total += t;
            woff += (ww < wid) ? t : 0u;
        }
        unsigned rank = running + woff + x - cnt;   // exclusive prefix
        while (word) {
            int b = __builtin_ctzll(word);
            word &= word - 1;
            if (rank < (unsigned)KPTS) {
                unsigned p = (unsigned)(w * 64 + b);
                unsigned rr = p >> 9, cc = p & 511u;
                ptsG[m * KPTS + rank] = (rr << 16) | cc;
            }
            rank++;
        }
        running += total;
        if (running >= (unsigned)KPTS) break;   // uniform -> safe
        __syncthreads();   // protect swv before next chunk
    }
}

// ---------------------------------------------------------------------------
// Kernel 3 (phase 1): single-wave Prim per image, RECORD-ONLY, ZERO LDS,
// BRANCHLESS (R9 lesson: uniform switch = +110cyc of branch bubbles).
// SELF-KILLING KEYS: store k' = (d2<<10)+idx-1024 (bias via sdot2 acc).
//   live: d2>=1 (distinct pixels) -> k' >= 0
//   dead: distance-to-self d2=0  -> k' = idx-1024 < 0
// Reduce = UNSIGNED min (negative = huge -> dead excluded);
// update = SIGNED min (negative wins -> dead stays dead == upd & ~in_tree).
// Extracting j makes j's next update d2(pj,pj)=0 -> self-kill: ZERO kill ops.
// Root (slot0,lane0) init d2(p0,p0)=0 -> auto in-tree. Extraction order is
// bit-identical to the reference (constant bias, monotone on live keys).
// ---------------------------------------------------------------------------
typedef short v2s __attribute__((ext_vector_type(2)));

__device__ __forceinline__ int dist2_packed(unsigned a, unsigned b) {
#if __has_builtin(__builtin_amdgcn_sdot2)
    v2s d = __builtin_bit_cast(v2s, a) - __builtin_bit_cast(v2s, b);
    return __builtin_amdgcn_sdot2(d, d, 0, false);
#else
    int dr = (int)(a >> 16) - (int)(b >> 16);
    int dc = (int)(a & 0xFFFFu) - (int)(b & 0xFFFFu);
    return __mul24(dr, dr) + __mul24(dc, dc);
#endif
}

template <int CTRL>
__device__ __forceinline__ unsigned umin_dpp(unsigned x) {
    unsigned o = (unsigned)__builtin_amdgcn_update_dpp((int)x, (int)x, CTRL,
                                                       0xf, 0xf, false);
    return o < x ? o : x;
}

__device__ __forceinline__ unsigned umin3(unsigned a, unsigned b, unsigned c) {
    unsigned t = a < b ? a : b;          // fuses to v_min3_u32
    return t < c ? t : c;
}

// biased key: coords pre-shifted <<5 so sdot2 gives d2<<10; acc = idx-1024
__device__ __forceinline__ unsigned mk_key(unsigned ps, unsigned qs, int izb) {
#if __has_builtin(__builtin_amdgcn_sdot2)
    v2s d = __builtin_bit_cast(v2s, ps) - __builtin_bit_cast(v2s, qs);
    return (unsigned)__builtin_amdgcn_sdot2(d, d, izb, false);
#else
    int dr = (int)(short)(ps >> 16) - (int)(short)(qs >> 16);
    int dc = (int)(short)(ps & 0xFFFFu) - (int)(short)(qs & 0xFFFFu);
    return (unsigned)(dr * dr + dc * dc + izb);
#endif
}

#define SLOT_INIT(s, ps, ks, iz)                                          \
    iz = ((s << 6) | lane) - 1024;      /* idx - 1024 (negative) */       \
    ps = base[(s << 6) | lane] << 5;    /* halves: r<<5 | c<<5 */         \
    ks = mk_key(ps, pt0s, iz);          /* slot0/lane0 self-kills */

#define SLOT_UPD(s, ps, ks, iz)                                           \
    { unsigned _nk = mk_key(ps, pjs, iz);                                 \
      ks = (unsigned)min((int)ks, (int)_nk); }  /* signed: dead wins */

#define INLANE_MIN16(res)                                                 \
    { unsigned _m0 = umin3(k0, k1, k2);                                   \
      unsigned _m1 = umin3(k3, k4, k5);                                   \
      unsigned _m2 = umin3(k6, k7, k8);                                   \
      unsigned _m3 = umin3(k9, k10, k11);                                 \
      unsigned _m4 = umin3(k12, k13, k14);                                \
      unsigned _ra = umin3(_m0, _m1, _m2);                                \
      unsigned _rb = umin3(_m3, _m4, k15);                                \
      res = _ra < _rb ? _ra : _rb; }

#define SEL16P(res)                                                       \
    { unsigned _a0 = b0 ? p1  : p0;                                       \
      unsigned _a1 = b0 ? p3  : p2;                                       \
      unsigned _a2 = b0 ? p5  : p4;                                       \
      unsigned _a3 = b0 ? p7  : p6;                                       \
      unsigned _a4 = b0 ? p9  : p8;                                       \
      unsigned _a5 = b0 ? p11 : p10;                                      \
      unsigned _a6 = b0 ? p13 : p12;                                      \
      unsigned _a7 = b0 ? p15 : p14;                                      \
      unsigned _c0 = b1 ? _a1 : _a0;                                      \
      unsigned _c1 = b1 ? _a3 : _a2;                                      \
      unsigned _c2 = b1 ? _a5 : _a4;                                      \
      unsigned _c3 = b1 ? _a7 : _a6;                                      \
      unsigned _e0 = b2 ? _c1 : _c0;                                      \
      unsigned _e1 = b2 ? _c3 : _c2;                                      \
      res = b3 ? _e1 : _e0; }

#define PIN16(P) asm volatile("" :                                        \
    "+v"(P##0), "+v"(P##1), "+v"(P##2),  "+v"(P##3),                      \
    "+v"(P##4), "+v"(P##5), "+v"(P##6),  "+v"(P##7),                      \
    "+v"(P##8), "+v"(P##9), "+v"(P##10), "+v"(P##11),                     \
    "+v"(P##12), "+v"(P##13), "+v"(P##14), "+v"(P##15))

__global__ __launch_bounds__(64, 1) void mst_kernel(const unsigned* __restrict__ ptsG,
                                                    unsigned* __restrict__ edgesG) {
    int lane = threadIdx.x;          // 0..63
    int m = blockIdx.x;
    const unsigned* base = ptsG + m * KPTS;
    unsigned pt0s = base[0] << 5;    // self point 0, shifted (uniform)

    unsigned k0,k1,k2,k3,k4,k5,k6,k7,k8,k9,k10,k11,k12,k13,k14,k15;
    unsigned p0,p1,p2,p3,p4,p5,p6,p7,p8,p9,p10,p11,p12,p13,p14,p15;
    int      i0,i1,i2,i3,i4,i5,i6,i7,i8,i9,i10,i11,i12,i13,i14,i15;

    SLOT_INIT(0,  p0,  k0,  i0);   SLOT_INIT(1,  p1,  k1,  i1);
    SLOT_INIT(2,  p2,  k2,  i2);   SLOT_INIT(3,  p3,  k3,  i3);
    SLOT_INIT(4,  p4,  k4,  i4);   SLOT_INIT(5,  p5,  k5,  i5);
    SLOT_INIT(6,  p6,  k6,  i6);   SLOT_INIT(7,  p7,  k7,  i7);
    SLOT_INIT(8,  p8,  k8,  i8);   SLOT_INIT(9,  p9,  k9,  i9);
    SLOT_INIT(10, p10, k10, i10);  SLOT_INIT(11, p11, k11, i11);
    SLOT_INIT(12, p12, k12, i12);  SLOT_INIT(13, p13, k13, i13);
    SLOT_INIT(14, p14, k14, i14);  SLOT_INIT(15, p15, k15, i15);

    unsigned* eout = edgesG + m * KPTS;
    unsigned rk;
    INLANE_MIN16(rk);

    unsigned acc = 0;                // per-lane edge accumulator (batch of 64)

    for (int it = 0; it < KPTS - 1; it++) {
        PIN16(p); PIN16(k);

        // ---- wave-64 min: 4 DPP row-folds + 4 readlane + scalar min ----
        rk = umin_dpp<0x111>(rk);   // row_shr:1
        rk = umin_dpp<0x112>(rk);   // row_shr:2
        rk = umin_dpp<0x114>(rk);   // row_shr:4
        rk = umin_dpp<0x118>(rk);   // row_shr:8 -> lane15 of each 16-row
        unsigned q0 = (unsigned)__builtin_amdgcn_readlane((int)rk, 15);
        unsigned q1 = (unsigned)__builtin_amdgcn_readlane((int)rk, 31);
        unsigned q2 = (unsigned)__builtin_amdgcn_readlane((int)rk, 47);
        unsigned q3 = (unsigned)__builtin_amdgcn_readlane((int)rk, 63);
        unsigned wa = q0 < q1 ? q0 : q1;
        unsigned wb = q2 < q3 ? q2 : q3;
        unsigned wk = (wa < wb ? wa : wb) + 1024u;   // unbias (scalar)

        unsigned j = wk & 1023u;
        int wslot = (int)(j >> 6);
        int wlane = (int)(j & 63u);

        // ---- pj (shifted coords) from register file: SEL16 + readlane ----
        bool b0 = (wslot & 1) != 0, b1 = (wslot & 2) != 0;
        bool b2 = (wslot & 4) != 0, b3 = (wslot & 8) != 0;
        unsigned selPay;
        SEL16P(selPay);
        unsigned pjs = (unsigned)__builtin_amdgcn_readlane((int)selPay, wlane);

        // ---- edge record: accumulate, bulk-store every 64 iters ----
        acc = (lane == (it & 63)) ? wk : acc;
        if ((it & 63) == 63)                 // uniform; full-wave coalesced
            eout[(it - 63) + lane] = acc;

        // ---- decrease-key; extracted slot self-kills (d2=0 -> negative) ----
        SLOT_UPD(0,  p0,  k0,  i0);   SLOT_UPD(1,  p1,  k1,  i1);
        SLOT_UPD(2,  p2,  k2,  i2);   SLOT_UPD(3,  p3,  k3,  i3);
        SLOT_UPD(4,  p4,  k4,  i4);   SLOT_UPD(5,  p5,  k5,  i5);
        SLOT_UPD(6,  p6,  k6,  i6);   SLOT_UPD(7,  p7,  k7,  i7);
        SLOT_UPD(8,  p8,  k8,  i8);   SLOT_UPD(9,  p9,  k9,  i9);
        SLOT_UPD(10, p10, k10, i10);  SLOT_UPD(11, p11, k11, i11);
        SLOT_UPD(12, p12, k12, i12);  SLOT_UPD(13, p13, k13, i13);
        SLOT_UPD(14, p14, k14, i14);  SLOT_UPD(15, p15, k15, i15);

        INLANE_MIN16(rk);                    // next iteration's per-lane min
    }
    // tail: iterations 960..1022 filled lanes 0..62 of the last batch
    if (lane < 63) eout[960 + lane] = acc;
}

// ---------------------------------------------------------------------------
// Kernel 4 (phase 2): recover src per edge + per-edge (Dp-Dm)^2.
// src[j] = earliest-extracted v with d2(v,j)==d2p (exact-int match) —
// provably identical to the reference's strict-'<' update history.
// ---------------------------------------------------------------------------
__global__ void recover_kernel(const unsigned* __restrict__ ptsG,
                               const unsigned* __restrict__ edgesG,
                               float* __restrict__ contrib) {
    __shared__ unsigned sS[KPTS];
    __shared__ unsigned sO[KPTS];
    __shared__ unsigned short sT[KPTS];   // extraction time + 1 (0 = root)
    int g = blockIdx.x, m = blockIdx.y;
    int tid = threadIdx.x;
    int partner = m ^ 1;

    for (int i = tid; i < KPTS; i += 256) {
        sS[i] = ptsG[m * KPTS + i];
        sO[i] = ptsG[partner * KPTS + i];
    }
    for (int e = tid; e < KPTS - 1; e += 256) {
        unsigned wkk = edgesG[m * KPTS + e];
        sT[wkk & 1023u] = (unsigned short)(e + 1);
    }
    if (tid == 0) sT[0] = 0;
    __syncthreads();

    int lane = tid & 63, w = tid >> 6;
    for (int k = 0; k < 16; k++) {
        int e = g * 64 + w * 16 + k;
        if (e >= KPTS - 1) break;            // only e=1023 (g=15,w=3,k=15)
        unsigned wk = edgesG[m * KPTS + e];
        unsigned j = wk & 1023u;
        unsigned d2p = wk >> 10;
        unsigned pj = sS[j];
        unsigned te1 = (unsigned)(e + 1);

        unsigned best = 0xFFFFFFFFu;
#pragma unroll
        for (int i = 0; i < 16; i++) {
            int v = i * 64 + lane;
            unsigned pv = sS[v];
            int d2 = dist2_packed(pv, pj);
            unsigned tv1 = (unsigned)sT[v];
            bool qual = ((unsigned)d2 == d2p) && (tv1 < te1);
            unsigned cand = qual ? ((tv1 << 10) | (unsigned)v) : 0xFFFFFFFFu;
            best = cand < best ? cand : best;
        }
#pragma unroll
        for (int dd = 32; dd; dd >>= 1) {
            unsigned o = (unsigned)__shfl_xor((int)best, dd, 64);
            best = o < best ? o : best;
        }
        unsigned vsrc = best & 1023u;
        if (lane == 0) {
            unsigned oj = sO[j], os = sO[vsrc];
            float Dp = __fsqrt_rn((float)d2p);
            float Dm = __fsqrt_rn((float)dist2_packed(oj, os));
            float diff = Dp - Dm;
            contrib[m * (KPTS - 1) + e] = diff * diff;
        }
    }
}

// ---------------------------------------------------------------------------
// Kernel 5: per-image f64 sum (extraction order, deterministic) -> loss
// ---------------------------------------------------------------------------
__global__ void final_kernel(const float* __restrict__ contrib,
                             float* __restrict__ out) {
    __shared__ double part[NIMG];
    int t = threadIdx.x;
    if (t < NIMG) {
        double s = 0.0;
        for (int e = 0; e < KPTS - 1; e++)
            s += (double)contrib[t * (KPTS - 1) + e];
        part[t] = sqrt(s);
    }
    __syncthreads();
    if (t == 0) {
        double tot = 0.0;
        for (int i = 0; i < NIMG; i++) tot += part[i];
        out[0] = (float)(0.1 * tot / 8.0);
    }
}

// ---------------------------------------------------------------------------
// ws layout:
//   [0,512K)     maskbits (lbp->select), then DEAD:
//   [0,64K)      edgesG   (mst->recover)   — overlaps dead maskbits
//   [64K,128K)   contrib  (recover->final) — overlaps dead maskbits
//   [512K,576K)  ptsG     (select->mst/recover)
// ---------------------------------------------------------------------------
extern "C" void kernel_launch(void* const* d_in, const int* in_sizes, int n_in,
                              void* d_out, int out_size, void* d_ws, size_t ws_size,
                              hipStream_t stream) {
    const float* mo = (const float*)d_in[1];   // model_output
    const float* lb = (const float*)d_in[2];   // labels

    unsigned long long* maskbits = (unsigned long long*)d_ws;
    unsigned* edgesG = (unsigned*)d_ws;
    float* contrib = (float*)((char*)d_ws + (size_t)64 * 1024);
    unsigned* ptsG = (unsigned*)((char*)d_ws + (size_t)NIMG * NWORDS * 8);
    float* out = (float*)d_out;

    lbp_kernel<<<dim3(NPIX / 256, NIMG), 256, 0, stream>>>(mo, lb, maskbits);
    select_kernel<<<NIMG, 256, 0, stream>>>(maskbits, ptsG);
    mst_kernel<<<NIMG, 64, 0, stream>>>(ptsG, edgesG);
    recover_kernel<<<dim3(16, NIMG), 256, 0, stream>>>(ptsG, edgesG, contrib);
    final_kernel<<<1, 64, 0, stream>>>(contrib, out);
}

// Round 13
// 435.962 us; speedup vs baseline: 1.2829x; 1.0325x over previous
//
#include <hip/hip_runtime.h>

#define HH 512
#define WW 512
#define NPIX (HH * WW)          // 262144
#define NIMG 16
#define KPTS 1024
#define NWORDS (NPIX / 64)      // 4096 u64 mask words per image

// ---------------------------------------------------------------------------
// Kernel 1: binarize + uniform LBP (P=8,R=1) — PURE BOOLEAN form.
// On a binary image the bilinear-threshold reduces exactly:
//   center=0 -> all 8 bits = 1 -> s=8 -> never masked  => maskbit needs b00
//   center=1 -> bit_k = AND of the nonzero-weight corners (even k: 1 nbr;
//               odd k: 4 corners). Rounding-independent: all-ones bilinear
//               sums to exactly 1.0 (1-fr exact for every r), any missing
//               corner subtracts >= 0.0858 >> ulp.
// Only the clamped 3x3 neighborhood is needed (9 loads, was 33).
// Edge cases r==0 / c==0: second row/col of the -A directions is index 1
// (= rp/cp), handled by the t2*/.c2 selects below.
// ---------------------------------------------------------------------------
__global__ void lbp_kernel(const float* __restrict__ mo,
                           const float* __restrict__ lb,
                           unsigned long long* __restrict__ maskbits) {
    int m = blockIdx.y;                    // image 0..15: even=pred, odd=mask
    int pix = blockIdx.x * blockDim.x + threadIdx.x;   // 0..262143
    int r = pix >> 9, c = pix & 511;
    int sample = m >> 1;
    const float* img = (m & 1) ? (lb + sample * NPIX) : (mo + sample * NPIX);
    float thr = (m & 1) ? 0.5f : 0.0f;     // sigmoid(x)>0.5 <=> x>0

    int rm = r - (r > 0), rp = r + (r < HH - 1);
    int cm = c - (c > 0), cp = c + (c < WW - 1);
    const float* rowm = img + rm * WW;
    const float* row0 = img + r  * WW;
    const float* rowp = img + rp * WW;

    bool bmm = rowm[cm] > thr, bm0 = rowm[c] > thr, bmp = rowm[cp] > thr;
    bool b0m = row0[cm] > thr, b00 = row0[c] > thr, b0p = row0[cp] > thr;
    bool bpm = rowp[cm] > thr, bp0 = rowp[c] > thr, bpp = rowp[cp] > thr;

    bool r0e = (r == 0), c0e = (c == 0);
    // dr=-A second row is min(rm+1,511): row r normally, row rp when r==0
    bool t2m = r0e ? bpm : b0m;    // B(row2, cm)
    bool t2c = r0e ? bp0 : b00;    // B(row2, c)
    bool t2p = r0e ? bpp : b0p;    // B(row2, cp)
    // dc=-A second col is min(cm+1,511): col c normally, col cp when c==0
    bool mc2 = c0e ? bmp : bm0;    // B(rm,  col2)
    bool tc2 = c0e ? t2p : t2c;    // B(row2,col2)
    bool zc2 = c0e ? b0p : b00;    // B(r,   col2)
    bool pc2 = c0e ? bpp : bp0;    // B(rp,  col2)

    unsigned bb =
        (b0p                     ?   1u : 0u)    // k=0: (r, c+1)
      | ((bm0 & bmp & t2c & t2p) ?   2u : 0u)    // k=1: rows(rm,row2) cols(c,cp)
      | (bm0                     ?   4u : 0u)    // k=2: (r-1, c)
      | ((bmm & mc2 & t2m & tc2) ?   8u : 0u)    // k=3: rows(rm,row2) cols(cm,col2)
      | (b0m                     ?  16u : 0u)    // k=4: (r, c-1)
      | ((b0m & zc2 & bpm & pc2) ?  32u : 0u)    // k=5: rows(r,rp) cols(cm,col2)
      | (bp0                     ?  64u : 0u)    // k=6: (r+1, c)
      | ((b0p & bp0 & bpp)       ? 128u : 0u);   // k=7: rows(r,rp) cols(c,cp)

    unsigned rol = ((bb << 1) | (bb >> 7)) & 0xFFu;
    int changes = __popc(bb ^ rol);
    int s = __popc(bb);
    bool maskbit = b00 && (changes <= 2) && (s < 5);   // lbp < THR(=5)

    unsigned long long w = __ballot(maskbit);
    if ((threadIdx.x & 63) == 0)
        maskbits[m * NWORDS + (pix >> 6)] = w;
}

// ---------------------------------------------------------------------------
// Kernel 2: stable row-major compaction to K=1024 packed points per image
// pts entry: (r<<16)|c ; zero-padded. Shfl scan + uniform early-exit once
// K points are found (random inputs -> chunk 0 already has ~2x K).
// ---------------------------------------------------------------------------
__global__ void select_kernel(const unsigned long long* __restrict__ maskbits,
                              unsigned* __restrict__ ptsG) {
    __shared__ unsigned swv[4];
    int m = blockIdx.x, tid = threadIdx.x;
    int lane = tid & 63, wid = tid >> 6;

    for (int i = tid; i < KPTS; i += 256) ptsG[m * KPTS + i] = 0u;
    __syncthreads();

    unsigned running = 0;
    for (int ch = 0; ch < 16; ch++) {
        int w = ch * 256 + tid;
        unsigned long long word = maskbits[m * NWORDS + w];
        unsigned cnt = (unsigned)__popcll(word);

        unsigned x = cnt;                    // intra-wave inclusive scan
#pragma unroll
        for (int d = 1; d < 64; d <<= 1) {
            unsigned y = (unsigned)__shfl_up((int)x, d, 64);
            x += (lane >= d) ? y : 0u;
        }
        if (lane == 63) swv[wid] = x;
        __syncthreads();
        unsigned woff = 0, total = 0;
#pragma unroll
        for (int ww = 0; ww < 4; ww++) {
            unsigned t = swv[ww];
            total += t;
            woff += (ww < wid) ? t : 0u;
        }
        unsigned rank = running + woff + x - cnt;   // exclusive prefix
        while (word) {
            int b = __builtin_ctzll(word);
            word &= word - 1;
            if (rank < (unsigned)KPTS) {
                unsigned p = (unsigned)(w * 64 + b);
                unsigned rr = p >> 9, cc = p & 511u;
                ptsG[m * KPTS + rank] = (rr << 16) | cc;
            }
            rank++;
        }
        running += total;
        if (running >= (unsigned)KPTS) break;   // uniform -> safe
        __syncthreads();   // protect swv before next chunk
    }
}

// ---------------------------------------------------------------------------
// Kernel 3 (phase 1): single-wave Prim per image, RECORD-ONLY, ZERO LDS,
// BRANCHLESS body. SELF-KILLING KEYS (R10): k' = (d2<<10)+idx-1024 via
// sdot2-accumulate on <<5-shifted coords; live k' >= 0, dead (self-dist)
// k' < 0. Reduce = unsigned min (dead excluded), update = signed min
// (dead stays dead). Extracted slot self-kills next update: zero kill ops.
// Edge record: cndmask accumulate + chunked batch stores (no store branch).
// ---------------------------------------------------------------------------
typedef short v2s __attribute__((ext_vector_type(2)));

__device__ __forceinline__ int dist2_packed(unsigned a, unsigned b) {
#if __has_builtin(__builtin_amdgcn_sdot2)
    v2s d = __builtin_bit_cast(v2s, a) - __builtin_bit_cast(v2s, b);
    return __builtin_amdgcn_sdot2(d, d, 0, false);
#else
    int dr = (int)(a >> 16) - (int)(b >> 16);
    int dc = (int)(a & 0xFFFFu) - (int)(b & 0xFFFFu);
    return __mul24(dr, dr) + __mul24(dc, dc);
#endif
}

template <int CTRL>
__device__ __forceinline__ unsigned umin_dpp(unsigned x) {
    unsigned o = (unsigned)__builtin_amdgcn_update_dpp((int)x, (int)x, CTRL,
                                                       0xf, 0xf, false);
    return o < x ? o : x;
}

__device__ __forceinline__ unsigned umin3(unsigned a, unsigned b, unsigned c) {
    unsigned t = a < b ? a : b;          // fuses to v_min3_u32
    return t < c ? t : c;
}

// biased key: coords pre-shifted <<5 so sdot2 gives d2<<10; acc = idx-1024
__device__ __forceinline__ unsigned mk_key(unsigned ps, unsigned qs, int izb) {
#if __has_builtin(__builtin_amdgcn_sdot2)
    v2s d = __builtin_bit_cast(v2s, ps) - __builtin_bit_cast(v2s, qs);
    return (unsigned)__builtin_amdgcn_sdot2(d, d, izb, false);
#else
    int dr = (int)(short)(ps >> 16) - (int)(short)(qs >> 16);
    int dc = (int)(short)(ps & 0xFFFFu) - (int)(short)(qs & 0xFFFFu);
    return (unsigned)(dr * dr + dc * dc + izb);
#endif
}

#define SLOT_INIT(s, ps, ks, iz)                                          \
    iz = ((s << 6) | lane) - 1024;      /* idx - 1024 (negative) */       \
    ps = base[(s << 6) | lane] << 5;    /* halves: r<<5 | c<<5 */         \
    ks = mk_key(ps, pt0s, iz);          /* slot0/lane0 self-kills */

#define SLOT_UPD(s, ps, ks, iz)                                           \
    { unsigned _nk = mk_key(ps, pjs, iz);                                 \
      ks = (unsigned)min((int)ks, (int)_nk); }  /* signed: dead wins */

#define INLANE_MIN16(res)                                                 \
    { unsigned _m0 = umin3(k0, k1, k2);                                   \
      unsigned _m1 = umin3(k3, k4, k5);                                   \
      unsigned _m2 = umin3(k6, k7, k8);                                   \
      unsigned _m3 = umin3(k9, k10, k11);                                 \
      unsigned _m4 = umin3(k12, k13, k14);                                \
      unsigned _ra = umin3(_m0, _m1, _m2);                                \
      unsigned _rb = umin3(_m3, _m4, k15);                                \
      res = _ra < _rb ? _ra : _rb; }

#define SEL16P(res)                                                       \
    { unsigned _a0 = b0 ? p1  : p0;                                       \
      unsigned _a1 = b0 ? p3  : p2;                                       \
      unsigned _a2 = b0 ? p5  : p4;                                       \
      unsigned _a3 = b0 ? p7  : p6;                                       \
      unsigned _a4 = b0 ? p9  : p8;                                       \
      unsigned _a5 = b0 ? p11 : p10;                                      \
      unsigned _a6 = b0 ? p13 : p12;                                      \
      unsigned _a7 = b0 ? p15 : p14;                                      \
      unsigned _c0 = b1 ? _a1 : _a0;                                      \
      unsigned _c1 = b1 ? _a3 : _a2;                                      \
      unsigned _c2 = b1 ? _a5 : _a4;                                      \
      unsigned _c3 = b1 ? _a7 : _a6;                                      \
      unsigned _e0 = b2 ? _c1 : _c0;                                      \
      unsigned _e1 = b2 ? _c3 : _c2;                                      \
      res = b3 ? _e1 : _e0; }

#define PIN16(P) asm volatile("" :                                        \
    "+v"(P##0), "+v"(P##1), "+v"(P##2),  "+v"(P##3),                      \
    "+v"(P##4), "+v"(P##5), "+v"(P##6),  "+v"(P##7),                      \
    "+v"(P##8), "+v"(P##9), "+v"(P##10), "+v"(P##11),                     \
    "+v"(P##12), "+v"(P##13), "+v"(P##14), "+v"(P##15))

__global__ __launch_bounds__(64, 1) void mst_kernel(const unsigned* __restrict__ ptsG,
                                                    unsigned* __restrict__ edgesG) {
    int lane = threadIdx.x;          // 0..63
    int m = blockIdx.x;
    const unsigned* base = ptsG + m * KPTS;
    unsigned pt0s = base[0] << 5;    // self point 0, shifted (uniform)

    unsigned k0,k1,k2,k3,k4,k5,k6,k7,k8,k9,k10,k11,k12,k13,k14,k15;
    unsigned p0,p1,p2,p3,p4,p5,p6,p7,p8,p9,p10,p11,p12,p13,p14,p15;
    int      i0,i1,i2,i3,i4,i5,i6,i7,i8,i9,i10,i11,i12,i13,i14,i15;

    SLOT_INIT(0,  p0,  k0,  i0);   SLOT_INIT(1,  p1,  k1,  i1);
    SLOT_INIT(2,  p2,  k2,  i2);   SLOT_INIT(3,  p3,  k3,  i3);
    SLOT_INIT(4,  p4,  k4,  i4);   SLOT_INIT(5,  p5,  k5,  i5);
    SLOT_INIT(6,  p6,  k6,  i6);   SLOT_INIT(7,  p7,  k7,  i7);
    SLOT_INIT(8,  p8,  k8,  i8);   SLOT_INIT(9,  p9,  k9,  i9);
    SLOT_INIT(10, p10, k10, i10);  SLOT_INIT(11, p11, k11, i11);
    SLOT_INIT(12, p12, k12, i12);  SLOT_INIT(13, p13, k13, i13);
    SLOT_INIT(14, p14, k14, i14);  SLOT_INIT(15, p15, k15, i15);

    unsigned* eout = edgesG + m * KPTS;
    unsigned rk;
    INLANE_MIN16(rk);

    unsigned acc = 0;                // per-lane edge accumulator (batch of 64)

    for (int chk = 0; chk < 16; chk++) {
        int tmax = (chk < 15) ? 64 : 63;     // 15*64 + 63 = 1023 iterations
        for (int t = 0; t < tmax; t++) {
            PIN16(p); PIN16(k);

            // ---- wave-64 min: 4 DPP row-folds + 4 readlane + scalar min ----
            rk = umin_dpp<0x111>(rk);   // row_shr:1
            rk = umin_dpp<0x112>(rk);   // row_shr:2
            rk = umin_dpp<0x114>(rk);   // row_shr:4
            rk = umin_dpp<0x118>(rk);   // row_shr:8 -> lane15 of each 16-row
            unsigned q0 = (unsigned)__builtin_amdgcn_readlane((int)rk, 15);
            unsigned q1 = (unsigned)__builtin_amdgcn_readlane((int)rk, 31);
            unsigned q2 = (unsigned)__builtin_amdgcn_readlane((int)rk, 47);
            unsigned q3 = (unsigned)__builtin_amdgcn_readlane((int)rk, 63);
            unsigned wa = q0 < q1 ? q0 : q1;
            unsigned wb = q2 < q3 ? q2 : q3;
            unsigned wk = (wa < wb ? wa : wb) + 1024u;   // unbias (scalar)

            unsigned j = wk & 1023u;
            int wslot = (int)(j >> 6);
            int wlane = (int)(j & 63u);

            // ---- pj (shifted coords) from register file: SEL16 + readlane --
            bool b0 = (wslot & 1) != 0, b1 = (wslot & 2) != 0;
            bool b2 = (wslot & 4) != 0, b3 = (wslot & 8) != 0;
            unsigned selPay;
            SEL16P(selPay);
            unsigned pjs = (unsigned)__builtin_amdgcn_readlane((int)selPay, wlane);

            // ---- edge record: cndmask accumulate into lane t ----
            acc = (lane == t) ? wk : acc;

            // ---- decrease-key; extracted slot self-kills (d2=0 -> neg) ----
            SLOT_UPD(0,  p0,  k0,  i0);   SLOT_UPD(1,  p1,  k1,  i1);
            SLOT_UPD(2,  p2,  k2,  i2);   SLOT_UPD(3,  p3,  k3,  i3);
            SLOT_UPD(4,  p4,  k4,  i4);   SLOT_UPD(5,  p5,  k5,  i5);
            SLOT_UPD(6,  p6,  k6,  i6);   SLOT_UPD(7,  p7,  k7,  i7);
            SLOT_UPD(8,  p8,  k8,  i8);   SLOT_UPD(9,  p9,  k9,  i9);
            SLOT_UPD(10, p10, k10, i10);  SLOT_UPD(11, p11, k11, i11);
            SLOT_UPD(12, p12, k12, i12);  SLOT_UPD(13, p13, k13, i13);
            SLOT_UPD(14, p14, k14, i14);  SLOT_UPD(15, p15, k15, i15);

            INLANE_MIN16(rk);               // next iteration's per-lane min
        }
        // full-wave coalesced batch store; chk=15 lane63 writes eout[1023]
        // (stale value) which is never read by recover_kernel.
        eout[(chk << 6) + lane] = acc;
    }
}

// ---------------------------------------------------------------------------
// Kernel 4 (phase 2): recover src per edge + per-edge (Dp-Dm)^2.
// src[j] = earliest-extracted v with d2(v,j)==d2p (exact-int match) —
// provably identical to the reference's strict-'<' update history.
// ---------------------------------------------------------------------------
__global__ void recover_kernel(const unsigned* __restrict__ ptsG,
                               const unsigned* __restrict__ edgesG,
                               float* __restrict__ contrib) {
    __shared__ unsigned sS[KPTS];
    __shared__ unsigned sO[KPTS];
    __shared__ unsigned short sT[KPTS];   // extraction time + 1 (0 = root)
    int g = blockIdx.x, m = blockIdx.y;
    int tid = threadIdx.x;
    int partner = m ^ 1;

    for (int i = tid; i < KPTS; i += 256) {
        sS[i] = ptsG[m * KPTS + i];
        sO[i] = ptsG[partner * KPTS + i];
    }
    for (int e = tid; e < KPTS - 1; e += 256) {
        unsigned wkk = edgesG[m * KPTS + e];
        sT[wkk & 1023u] = (unsigned short)(e + 1);
    }
    if (tid == 0) sT[0] = 0;
    __syncthreads();

    int lane = tid & 63, w = tid >> 6;
    for (int k = 0; k < 16; k++) {
        int e = g * 64 + w * 16 + k;
        if (e >= KPTS - 1) break;            // only e=1023 (g=15,w=3,k=15)
        unsigned wk = edgesG[m * KPTS + e];
        unsigned j = wk & 1023u;
        unsigned d2p = wk >> 10;
        unsigned pj = sS[j];
        unsigned te1 = (unsigned)(e + 1);

        unsigned best = 0xFFFFFFFFu;
#pragma unroll
        for (int i = 0; i < 16; i++) {
            int v = i * 64 + lane;
            unsigned pv = sS[v];
            int d2 = dist2_packed(pv, pj);
            unsigned tv1 = (unsigned)sT[v];
            bool qual = ((unsigned)d2 == d2p) && (tv1 < te1);
            unsigned cand = qual ? ((tv1 << 10) | (unsigned)v) : 0xFFFFFFFFu;
            best = cand < best ? cand : best;
        }
#pragma unroll
        for (int dd = 32; dd; dd >>= 1) {
            unsigned o = (unsigned)__shfl_xor((int)best, dd, 64);
            best = o < best ? o : best;
        }
        unsigned vsrc = best & 1023u;
        if (lane == 0) {
            unsigned oj = sO[j], os = sO[vsrc];
            float Dp = __fsqrt_rn((float)d2p);
            float Dm = __fsqrt_rn((float)dist2_packed(oj, os));
            float diff = Dp - Dm;
            contrib[m * (KPTS - 1) + e] = diff * diff;
        }
    }
}

// ---------------------------------------------------------------------------
// Kernel 5: per-image f64 sum (extraction order, deterministic) -> loss
// ---------------------------------------------------------------------------
__global__ void final_kernel(const float* __restrict__ contrib,
                             float* __restrict__ out) {
    __shared__ double part[NIMG];
    int t = threadIdx.x;
    if (t < NIMG) {
        double s = 0.0;
        for (int e = 0; e < KPTS - 1; e++)
            s += (double)contrib[t * (KPTS - 1) + e];
        part[t] = sqrt(s);
    }
    __syncthreads();
    if (t == 0) {
        double tot = 0.0;
        for (int i = 0; i < NIMG; i++) tot += part[i];
        out[0] = (float)(0.1 * tot / 8.0);
    }
}

// ---------------------------------------------------------------------------
// ws layout:
//   [0,512K)     maskbits (lbp->select), then DEAD:
//   [0,64K)      edgesG   (mst->recover)   — overlaps dead maskbits
//   [64K,128K)   contrib  (recover->final) — overlaps dead maskbits
//   [512K,576K)  ptsG     (select->mst/recover)
// ---------------------------------------------------------------------------
extern "C" void kernel_launch(void* const* d_in, const int* in_sizes, int n_in,
                              void* d_out, int out_size, void* d_ws, size_t ws_size,
                              hipStream_t stream) {
    const float* mo = (const float*)d_in[1];   // model_output
    const float* lb = (const float*)d_in[2];   // labels

    unsigned long long* maskbits = (unsigned long long*)d_ws;
    unsigned* edgesG = (unsigned*)d_ws;
    float* contrib = (float*)((char*)d_ws + (size_t)64 * 1024);
    unsigned* ptsG = (unsigned*)((char*)d_ws + (size_t)NIMG * NWORDS * 8);
    float* out = (float*)d_out;

    lbp_kernel<<<dim3(NPIX / 256, NIMG), 256, 0, stream>>>(mo, lb, maskbits);
    select_kernel<<<NIMG, 256, 0, stream>>>(maskbits, ptsG);
    mst_kernel<<<NIMG, 64, 0, stream>>>(ptsG, edgesG);
    recover_kernel<<<dim3(16, NIMG), 256, 0, stream>>>(ptsG, edgesG, contrib);
    final_kernel<<<1, 64, 0, stream>>>(contrib, out);
}